// Round 2
// baseline (11257.085 us; speedup 1.0000x reference)
//
#include <hip/hip_runtime.h>

#define NN 100000
#define NE 1600000
#define IN_CH 128
#define EAC 16
#define CAT 144      // IN_CH + EAC
#define MID 128
#define OUTC 128

#define TILE 64
#define THREADS 256
#define FSTR 145     // feat LDS stride (odd -> conflict-free column access)
#define HSTR 129     // h1 LDS stride (odd)

// ---------------- Edge kernel: h = MLP1(concat(x[col], ea)); scatter-add into summed[row]; count ----------------
__global__ __launch_bounds__(THREADS, 2)
void edge_kernel(const float* __restrict__ x,
                 const int* __restrict__ eidx,       // [2, NE]: [0]=row(dst), [1]=col(src)
                 const float* __restrict__ ea,       // [NE, 16]
                 const float* __restrict__ W1, const float* __restrict__ b1,
                 const float* __restrict__ W2, const float* __restrict__ b2,
                 float* __restrict__ summed, float* __restrict__ cnt)
{
    __shared__ float feat[TILE * FSTR];
    __shared__ float h1[TILE * HSTR];
    __shared__ int s_col[TILE];
    __shared__ int s_row[TILE];

    const int tid = threadIdx.x;
    const long e0 = (long)blockIdx.x * TILE;

    // ---- Phase 0: stage edge indices (NE divisible by TILE, no tail)
    if (tid < TILE)              s_col[tid] = eidx[NE + e0 + tid];
    else if (tid < 2 * TILE)     s_row[tid - TILE] = eidx[e0 + (tid - TILE)];
    __syncthreads();

    // ---- Phase 1: gather concat(x[col], edge_attr) into LDS, float4 granularity
    // 64 edges x 36 float4 (32 from x, 4 from ea) = 2304 float4
    for (int i = tid; i < TILE * 36; i += THREADS) {
        int e = i / 36;
        int seg = i - e * 36;
        float4 v;
        if (seg < 32) {
            int src = s_col[e];
            v = *(const float4*)&x[(size_t)src * IN_CH + seg * 4];
        } else {
            v = *(const float4*)&ea[(size_t)(e0 + e) * EAC + (seg - 32) * 4];
        }
        int base = e * FSTR + seg * 4;
        feat[base + 0] = v.x; feat[base + 1] = v.y;
        feat[base + 2] = v.z; feat[base + 3] = v.w;
    }
    __syncthreads();

    const int lane = tid & 63;
    const int wv = __builtin_amdgcn_readfirstlane(tid >> 6);  // wave-uniform -> scalar W loads

    // ---- Phase 2: h1 = ReLU(feat @ W1 + b1). lane = edge; wave owns 32 channels (2 groups of 16)
    {
        const float* fl = &feat[lane * FSTR];
        for (int g = 0; g < 2; ++g) {
            int ob = wv * 32 + g * 16;   // wave-uniform channel base
            float acc[16];
            #pragma unroll
            for (int u = 0; u < 16; ++u) acc[u] = b1[ob + u];
            #pragma unroll 4
            for (int k = 0; k < CAT; ++k) {
                float f = fl[k];
                const float* wr = &W1[(size_t)k * MID + ob];
                #pragma unroll
                for (int u = 0; u < 16; ++u) acc[u] = fmaf(f, wr[u], acc[u]);
            }
            #pragma unroll
            for (int u = 0; u < 16; ++u) h1[lane * HSTR + ob + u] = fmaxf(acc[u], 0.f);
        }
    }
    __syncthreads();

    // ---- Phase 3: y = h1 @ W2 + b2; atomic scatter into summed[row]
    {
        const int dst = s_row[lane];
        const float* hl = &h1[lane * HSTR];
        for (int g = 0; g < 2; ++g) {
            int ob = wv * 32 + g * 16;
            float acc[16];
            #pragma unroll
            for (int u = 0; u < 16; ++u) acc[u] = b2[ob + u];
            #pragma unroll 4
            for (int k = 0; k < MID; ++k) {
                float f = hl[k];
                const float* wr = &W2[(size_t)k * MID + ob];
                #pragma unroll
                for (int u = 0; u < 16; ++u) acc[u] = fmaf(f, wr[u], acc[u]);
            }
            float* srow = &summed[(size_t)dst * MID + ob];
            #pragma unroll
            for (int u = 0; u < 16; ++u) atomicAdd(&srow[u], acc[u]);
        }
        if (wv == 0) atomicAdd(&cnt[dst], 1.0f);
    }
}

// ---------------- Node kernel: out = MLP2(summed/max(cnt,1)) ----------------
__global__ __launch_bounds__(THREADS, 2)
void node_kernel(const float* __restrict__ summed, const float* __restrict__ cnt,
                 const float* __restrict__ W3, const float* __restrict__ b3,
                 const float* __restrict__ W4, const float* __restrict__ b4,
                 float* __restrict__ out)
{
    __shared__ float feat[TILE * HSTR];
    __shared__ float h1[TILE * HSTR];

    const int tid = threadIdx.x;
    const long n0 = (long)blockIdx.x * TILE;
    const int nn = (int)min((long)TILE, (long)NN - n0);

    // load mean features: 64 nodes x 32 float4
    for (int i = tid; i < TILE * 32; i += THREADS) {
        int e = i >> 5, seg = i & 31;
        float4 v = make_float4(0.f, 0.f, 0.f, 0.f);
        if (e < nn) {
            v = *(const float4*)&summed[(size_t)(n0 + e) * MID + seg * 4];
            float inv = 1.0f / fmaxf(cnt[n0 + e], 1.0f);
            v.x *= inv; v.y *= inv; v.z *= inv; v.w *= inv;
        }
        int base = e * HSTR + seg * 4;
        feat[base + 0] = v.x; feat[base + 1] = v.y;
        feat[base + 2] = v.z; feat[base + 3] = v.w;
    }
    __syncthreads();

    const int lane = tid & 63;
    const int wv = __builtin_amdgcn_readfirstlane(tid >> 6);

    {
        const float* fl = &feat[lane * HSTR];
        for (int g = 0; g < 2; ++g) {
            int ob = wv * 32 + g * 16;
            float acc[16];
            #pragma unroll
            for (int u = 0; u < 16; ++u) acc[u] = b3[ob + u];
            #pragma unroll 4
            for (int k = 0; k < MID; ++k) {
                float f = fl[k];
                const float* wr = &W3[(size_t)k * MID + ob];
                #pragma unroll
                for (int u = 0; u < 16; ++u) acc[u] = fmaf(f, wr[u], acc[u]);
            }
            #pragma unroll
            for (int u = 0; u < 16; ++u) h1[lane * HSTR + ob + u] = fmaxf(acc[u], 0.f);
        }
    }
    __syncthreads();

    {
        const float* hl = &h1[lane * HSTR];
        for (int g = 0; g < 2; ++g) {
            int ob = wv * 32 + g * 16;
            float acc[16];
            #pragma unroll
            for (int u = 0; u < 16; ++u) acc[u] = b4[ob + u];
            #pragma unroll 4
            for (int k = 0; k < MID; ++k) {
                float f = hl[k];
                const float* wr = &W4[(size_t)k * MID + ob];
                #pragma unroll
                for (int u = 0; u < 16; ++u) acc[u] = fmaf(f, wr[u], acc[u]);
            }
            if (lane < nn) {
                float* orow = &out[(size_t)(n0 + lane) * OUTC + ob];
                #pragma unroll
                for (int u = 0; u < 16; ++u) orow[u] = acc[u];
            }
        }
    }
}

extern "C" void kernel_launch(void* const* d_in, const int* in_sizes, int n_in,
                              void* d_out, int out_size, void* d_ws, size_t ws_size,
                              hipStream_t stream) {
    const float* x    = (const float*)d_in[0];
    const int*   eidx = (const int*)d_in[1];
    const float* ea   = (const float*)d_in[2];
    // d_in[3] = batch (unused)
    const float* W1 = (const float*)d_in[4];
    const float* b1 = (const float*)d_in[5];
    const float* W2 = (const float*)d_in[6];
    const float* b2 = (const float*)d_in[7];
    const float* W3 = (const float*)d_in[8];
    const float* b3 = (const float*)d_in[9];
    const float* W4 = (const float*)d_in[10];
    const float* b4 = (const float*)d_in[11];
    float* out = (float*)d_out;

    float* summed = (float*)d_ws;                       // [NN, MID]
    float* cnt    = summed + (size_t)NN * MID;          // [NN]

    size_t zero_bytes = ((size_t)NN * MID + NN) * sizeof(float);
    hipMemsetAsync(d_ws, 0, zero_bytes, stream);

    edge_kernel<<<NE / TILE, THREADS, 0, stream>>>(
        x, eidx, ea, W1, b1, W2, b2, summed, cnt);

    node_kernel<<<(NN + TILE - 1) / TILE, THREADS, 0, stream>>>(
        summed, cnt, W3, b3, W4, b4, out);
}

// Round 3
// 1843.283 us; speedup vs baseline: 6.1071x; 6.1071x over previous
//
#include <hip/hip_runtime.h>

#define NN 100000
#define NE 1600000
#define IN_CH 128
#define EAC 16
#define CAT 144      // IN_CH + EAC
#define MID 128
#define OUTC 128

#define TILE 64
#define THREADS 256
#define FSTR 145     // feat LDS stride (odd -> conflict-free column access)
#define HSTR 129     // h1 LDS stride (odd)

__device__ __forceinline__ void atomic_add_f32(float* p, float v) {
    unsafeAtomicAdd(p, v);   // native global_atomic_add_f32 (no CAS loop)
}

// ---------------- Edge kernel: h1 = ReLU(concat(x[col], ea) @ W1 + b1); coalesced scatter-add into sumh[row] ----------------
// (W2/b2 hoisted through the segment-sum into the node kernel: sum(h1@W2+b2) = sum(h1)@W2 + cnt*b2)
__global__ __launch_bounds__(THREADS, 2)
void edge_kernel(const float* __restrict__ x,
                 const int* __restrict__ eidx,       // [2, NE]: [0]=row(dst), [1]=col(src)
                 const float* __restrict__ ea,       // [NE, 16]
                 const float* __restrict__ W1, const float* __restrict__ b1,
                 float* __restrict__ sumh, float* __restrict__ cnt)
{
    __shared__ float feat[TILE * FSTR];
    __shared__ float h1[TILE * HSTR];
    __shared__ int s_col[TILE];
    __shared__ int s_row[TILE];

    const int tid = threadIdx.x;
    const long e0 = (long)blockIdx.x * TILE;

    // ---- Phase 0: stage edge indices (NE divisible by TILE, no tail)
    if (tid < TILE)              s_col[tid] = eidx[NE + e0 + tid];
    else if (tid < 2 * TILE)     s_row[tid - TILE] = eidx[e0 + (tid - TILE)];
    __syncthreads();

    // ---- Phase 1: gather concat(x[col], edge_attr) into LDS, float4 granularity
    for (int i = tid; i < TILE * 36; i += THREADS) {
        int e = i / 36;
        int seg = i - e * 36;
        float4 v;
        if (seg < 32) {
            int src = s_col[e];
            v = *(const float4*)&x[(size_t)src * IN_CH + seg * 4];
        } else {
            v = *(const float4*)&ea[(size_t)(e0 + e) * EAC + (seg - 32) * 4];
        }
        int base = e * FSTR + seg * 4;
        feat[base + 0] = v.x; feat[base + 1] = v.y;
        feat[base + 2] = v.z; feat[base + 3] = v.w;
    }
    __syncthreads();

    const int lane = tid & 63;
    const int wv = __builtin_amdgcn_readfirstlane(tid >> 6);  // wave-uniform -> scalar W loads

    // ---- Phase 2: h1 = ReLU(feat @ W1 + b1). lane = edge; wave owns 32 channels (2 groups of 16)
    {
        const float* fl = &feat[lane * FSTR];
        for (int g = 0; g < 2; ++g) {
            int ob = wv * 32 + g * 16;   // wave-uniform channel base
            float acc[16];
            #pragma unroll
            for (int u = 0; u < 16; ++u) acc[u] = b1[ob + u];
            #pragma unroll 4
            for (int k = 0; k < CAT; ++k) {
                float f = fl[k];
                const float* wr = &W1[(size_t)k * MID + ob];
                #pragma unroll
                for (int u = 0; u < 16; ++u) acc[u] = fmaf(f, wr[u], acc[u]);
            }
            #pragma unroll
            for (int u = 0; u < 16; ++u) h1[lane * HSTR + ob + u] = fmaxf(acc[u], 0.f);
        }
    }
    __syncthreads();

    // ---- Phase 3: COALESCED scatter. Each wave-instr: 64 lanes = 64 consecutive channels of ONE dst row.
    {
        const int c  = tid & 127;     // channel
        const int eo = tid >> 7;      // 0/1: even/odd edges
        #pragma unroll 4
        for (int e2 = 0; e2 < TILE / 2; ++e2) {
            int e = eo + e2 * 2;
            int dst = s_row[e];                        // broadcast (LDS, uniform per wave)
            float v = h1[e * HSTR + c];                // stride-1 across lanes: conflict-free
            atomic_add_f32(&sumh[(size_t)dst * MID + c], v);
        }
        if (tid < TILE) atomic_add_f32(&cnt[s_row[tid]], 1.0f);
    }
}

// ---------------- Node kernel: mean = (sumh/max(cnt,1))@W2 + (cnt>0)*b2 ; out = ReLU(mean@W3+b3)@W4+b4 ----------------
__global__ __launch_bounds__(THREADS, 2)
void node_kernel(const float* __restrict__ sumh, const float* __restrict__ cnt,
                 const float* __restrict__ W2, const float* __restrict__ b2,
                 const float* __restrict__ W3, const float* __restrict__ b3,
                 const float* __restrict__ W4, const float* __restrict__ b4,
                 float* __restrict__ out)
{
    __shared__ float bufA[TILE * HSTR];
    __shared__ float bufB[TILE * HSTR];
    __shared__ float s_flag[TILE];

    const int tid = threadIdx.x;
    const long n0 = (long)blockIdx.x * TILE;
    const int nn = (int)min((long)TILE, (long)NN - n0);

    // ---- load meanh = sumh / max(cnt,1) into bufA; record flag = (cnt>0)
    if (tid < TILE) {
        float c = (tid < nn) ? cnt[n0 + tid] : 0.f;
        s_flag[tid] = (c > 0.f) ? 1.f : 0.f;
    }
    __syncthreads();
    for (int i = tid; i < TILE * 32; i += THREADS) {
        int e = i >> 5, seg = i & 31;
        float4 v = make_float4(0.f, 0.f, 0.f, 0.f);
        if (e < nn) {
            v = *(const float4*)&sumh[(size_t)(n0 + e) * MID + seg * 4];
            float cf = s_flag[e];
            // inv = 1/max(cnt,1); when cnt==0 flag=0 and sumh==0 anyway
            float cv = cnt[n0 + e];
            float inv = 1.0f / fmaxf(cv, 1.0f);
            (void)cf;
            v.x *= inv; v.y *= inv; v.z *= inv; v.w *= inv;
        }
        int base = e * HSTR + seg * 4;
        bufA[base + 0] = v.x; bufA[base + 1] = v.y;
        bufA[base + 2] = v.z; bufA[base + 3] = v.w;
    }
    __syncthreads();

    const int lane = tid & 63;
    const int wv = __builtin_amdgcn_readfirstlane(tid >> 6);

    // ---- mean = bufA @ W2 + flag*b2  -> bufB   (no activation)
    {
        const float* fl = &bufA[lane * HSTR];
        const float flag = s_flag[lane];
        for (int g = 0; g < 2; ++g) {
            int ob = wv * 32 + g * 16;
            float acc[16];
            #pragma unroll
            for (int u = 0; u < 16; ++u) acc[u] = flag * b2[ob + u];
            #pragma unroll 4
            for (int k = 0; k < MID; ++k) {
                float f = fl[k];
                const float* wr = &W2[(size_t)k * MID + ob];
                #pragma unroll
                for (int u = 0; u < 16; ++u) acc[u] = fmaf(f, wr[u], acc[u]);
            }
            #pragma unroll
            for (int u = 0; u < 16; ++u) bufB[lane * HSTR + ob + u] = acc[u];
        }
    }
    __syncthreads();

    // ---- h2 = ReLU(bufB @ W3 + b3) -> bufA
    {
        const float* fl = &bufB[lane * HSTR];
        for (int g = 0; g < 2; ++g) {
            int ob = wv * 32 + g * 16;
            float acc[16];
            #pragma unroll
            for (int u = 0; u < 16; ++u) acc[u] = b3[ob + u];
            #pragma unroll 4
            for (int k = 0; k < MID; ++k) {
                float f = fl[k];
                const float* wr = &W3[(size_t)k * MID + ob];
                #pragma unroll
                for (int u = 0; u < 16; ++u) acc[u] = fmaf(f, wr[u], acc[u]);
            }
            #pragma unroll
            for (int u = 0; u < 16; ++u) bufA[lane * HSTR + ob + u] = fmaxf(acc[u], 0.f);
        }
    }
    __syncthreads();

    // ---- out = bufA @ W4 + b4 -> global
    {
        const float* fl = &bufA[lane * HSTR];
        for (int g = 0; g < 2; ++g) {
            int ob = wv * 32 + g * 16;
            float acc[16];
            #pragma unroll
            for (int u = 0; u < 16; ++u) acc[u] = b4[ob + u];
            #pragma unroll 4
            for (int k = 0; k < MID; ++k) {
                float f = fl[k];
                const float* wr = &W4[(size_t)k * MID + ob];
                #pragma unroll
                for (int u = 0; u < 16; ++u) acc[u] = fmaf(f, wr[u], acc[u]);
            }
            if (lane < nn) {
                float* orow = &out[(size_t)(n0 + lane) * OUTC + ob];
                #pragma unroll
                for (int u = 0; u < 16; ++u) orow[u] = acc[u];
            }
        }
    }
}

extern "C" void kernel_launch(void* const* d_in, const int* in_sizes, int n_in,
                              void* d_out, int out_size, void* d_ws, size_t ws_size,
                              hipStream_t stream) {
    const float* x    = (const float*)d_in[0];
    const int*   eidx = (const int*)d_in[1];
    const float* ea   = (const float*)d_in[2];
    // d_in[3] = batch (unused)
    const float* W1 = (const float*)d_in[4];
    const float* b1 = (const float*)d_in[5];
    const float* W2 = (const float*)d_in[6];
    const float* b2 = (const float*)d_in[7];
    const float* W3 = (const float*)d_in[8];
    const float* b3 = (const float*)d_in[9];
    const float* W4 = (const float*)d_in[10];
    const float* b4 = (const float*)d_in[11];
    float* out = (float*)d_out;

    float* sumh = (float*)d_ws;                        // [NN, MID]  (sum of h1 per dst)
    float* cnt  = sumh + (size_t)NN * MID;             // [NN]

    size_t zero_bytes = ((size_t)NN * MID + NN) * sizeof(float);
    hipMemsetAsync(d_ws, 0, zero_bytes, stream);

    edge_kernel<<<NE / TILE, THREADS, 0, stream>>>(
        x, eidx, ea, W1, b1, sumh, cnt);

    node_kernel<<<(NN + TILE - 1) / TILE, THREADS, 0, stream>>>(
        sumh, cnt, W2, b2, W3, b3, W4, b4, out);
}

// Round 4
// 1447.103 us; speedup vs baseline: 7.7790x; 1.2738x over previous
//
#include <hip/hip_runtime.h>

#define NN 100000
#define NE 1600000
#define IN_CH 128
#define EAC 16
#define CAT 144      // IN_CH + EAC
#define MID 128
#define OUTC 128

#define TILE 64
#define THREADS 256
#define FSTR 145     // feat LDS stride (odd -> conflict-free column access)
#define H1STR 129    // h1 LDS stride (odd); TILE*H1STR (8256) <= TILE*FSTR (9280)

__device__ __forceinline__ void atomic_add_f32(float* p, float v) {
    unsafeAtomicAdd(p, v);   // native global_atomic_add_f32 (no CAS loop)
}

// ---------------- Edge kernel: h1 = ReLU(concat(x[col], ea) @ W1 + b1); coalesced scatter-add into sumh[row] ----------------
// Single LDS buffer reused: feat (phase 1-2) then h1-transpose staging (phase 3).
__global__ __launch_bounds__(THREADS, 4)
void edge_kernel(const float* __restrict__ x,
                 const int* __restrict__ eidx,       // [2, NE]: [0]=row(dst), [1]=col(src)
                 const float* __restrict__ ea,       // [NE, 16]
                 const float* __restrict__ W1, const float* __restrict__ b1,
                 float* __restrict__ sumh, float* __restrict__ cnt)
{
    __shared__ float buf[TILE * FSTR];   // 37120 B, dual-purpose
    __shared__ int s_col[TILE];
    __shared__ int s_row[TILE];

    const int tid = threadIdx.x;
    const long e0 = (long)blockIdx.x * TILE;

    // ---- Phase 0: stage edge indices (NE divisible by TILE, no tail)
    if (tid < TILE)              s_col[tid] = eidx[NE + e0 + tid];
    else if (tid < 2 * TILE)     s_row[tid - TILE] = eidx[e0 + (tid - TILE)];
    __syncthreads();

    // ---- Phase 1: gather concat(x[col], edge_attr) into buf, float4 granularity
    for (int i = tid; i < TILE * 36; i += THREADS) {
        int e = i / 36;
        int seg = i - e * 36;
        float4 v;
        if (seg < 32) {
            v = *(const float4*)&x[(size_t)s_col[e] * IN_CH + seg * 4];
        } else {
            v = *(const float4*)&ea[(size_t)(e0 + e) * EAC + (seg - 32) * 4];
        }
        int base = e * FSTR + seg * 4;
        buf[base + 0] = v.x; buf[base + 1] = v.y;
        buf[base + 2] = v.z; buf[base + 3] = v.w;
    }
    __syncthreads();

    const int lane = tid & 63;
    const int wv = __builtin_amdgcn_readfirstlane(tid >> 6);  // wave-uniform -> scalar W loads
    const int ob = wv * 32;                                   // wave's 32 output channels

    // ---- Phase 2: acc = ReLU(feat @ W1 + b1), lane = edge, 32 channels per wave, held in regs
    float acc[32];
    {
        const float* fl = &buf[lane * FSTR];
        #pragma unroll
        for (int u = 0; u < 32; ++u) acc[u] = b1[ob + u];
        #pragma unroll 2
        for (int k = 0; k < CAT; ++k) {
            float f = fl[k];
            const float* wr = &W1[(size_t)k * MID + ob];
            #pragma unroll
            for (int u = 0; u < 32; ++u) acc[u] = fmaf(f, wr[u], acc[u]);
        }
        #pragma unroll
        for (int u = 0; u < 32; ++u) acc[u] = fmaxf(acc[u], 0.f);
    }
    __syncthreads();     // all waves done READING buf (feat)

    // ---- repurpose buf as h1[64][H1STR]
    {
        float* hw = &buf[lane * H1STR + ob];   // bank = (lane+ob+u)%32: conflict-free
        #pragma unroll
        for (int u = 0; u < 32; ++u) hw[u] = acc[u];
    }
    __syncthreads();

    // ---- Phase 3: COALESCED scatter. Each wave-instr: 64 lanes = 64 consecutive channels of ONE dst row.
    {
        const int c  = tid & 127;     // channel
        const int eo = tid >> 7;      // 0/1: even/odd edges
        #pragma unroll 4
        for (int e2 = 0; e2 < TILE / 2; ++e2) {
            int e = eo + e2 * 2;
            int dst = s_row[e];                        // LDS broadcast, wave-uniform
            float v = buf[e * H1STR + c];              // (e+c)%32: 2-way max, free
            atomic_add_f32(&sumh[(size_t)dst * MID + c], v);
        }
        if (tid < TILE) atomic_add_f32(&cnt[s_row[tid]], 1.0f);
    }
}

// ---------------- Node kernel: mean = (sumh/max(cnt,1))@W2 + (cnt>0)*b2 ; out = ReLU(mean@W3+b3)@W4+b4 ----------------
// Single LDS buffer; GEMM results carried in registers across syncs.
__global__ __launch_bounds__(THREADS, 4)
void node_kernel(const float* __restrict__ sumh, const float* __restrict__ cnt,
                 const float* __restrict__ W2, const float* __restrict__ b2,
                 const float* __restrict__ W3, const float* __restrict__ b3,
                 const float* __restrict__ W4, const float* __restrict__ b4,
                 float* __restrict__ out)
{
    __shared__ float buf[TILE * H1STR];   // 33024 B, reused across all 3 GEMMs
    __shared__ float s_flag[TILE];

    const int tid = threadIdx.x;
    const long n0 = (long)blockIdx.x * TILE;
    const int nn = (int)min((long)TILE, (long)NN - n0);

    if (tid < TILE) {
        float c = (tid < nn) ? cnt[n0 + tid] : 0.f;
        s_flag[tid] = (c > 0.f) ? 1.f : 0.f;
    }

    // ---- load meanh = sumh / max(cnt,1) into buf
    for (int i = tid; i < TILE * 32; i += THREADS) {
        int e = i >> 5, seg = i & 31;
        float4 v = make_float4(0.f, 0.f, 0.f, 0.f);
        if (e < nn) {
            v = *(const float4*)&sumh[(size_t)(n0 + e) * MID + seg * 4];
            float inv = 1.0f / fmaxf(cnt[n0 + e], 1.0f);
            v.x *= inv; v.y *= inv; v.z *= inv; v.w *= inv;
        }
        int base = e * H1STR + seg * 4;
        buf[base + 0] = v.x; buf[base + 1] = v.y;
        buf[base + 2] = v.z; buf[base + 3] = v.w;
    }
    __syncthreads();

    const int lane = tid & 63;
    const int wv = __builtin_amdgcn_readfirstlane(tid >> 6);
    const int ob = wv * 32;

    float acc[32];

    // ---- GEMM A: mean = buf @ W2 + flag*b2 (no activation), result in regs
    {
        const float* fl = &buf[lane * H1STR];
        const float flag = s_flag[lane];
        #pragma unroll
        for (int u = 0; u < 32; ++u) acc[u] = flag * b2[ob + u];
        #pragma unroll 2
        for (int k = 0; k < MID; ++k) {
            float f = fl[k];
            const float* wr = &W2[(size_t)k * MID + ob];
            #pragma unroll
            for (int u = 0; u < 32; ++u) acc[u] = fmaf(f, wr[u], acc[u]);
        }
    }
    __syncthreads();
    {
        float* hw = &buf[lane * H1STR + ob];
        #pragma unroll
        for (int u = 0; u < 32; ++u) hw[u] = acc[u];
    }
    __syncthreads();

    // ---- GEMM B: h2 = ReLU(buf @ W3 + b3), result in regs
    {
        const float* fl = &buf[lane * H1STR];
        #pragma unroll
        for (int u = 0; u < 32; ++u) acc[u] = b3[ob + u];
        #pragma unroll 2
        for (int k = 0; k < MID; ++k) {
            float f = fl[k];
            const float* wr = &W3[(size_t)k * MID + ob];
            #pragma unroll
            for (int u = 0; u < 32; ++u) acc[u] = fmaf(f, wr[u], acc[u]);
        }
        #pragma unroll
        for (int u = 0; u < 32; ++u) acc[u] = fmaxf(acc[u], 0.f);
    }
    __syncthreads();
    {
        float* hw = &buf[lane * H1STR + ob];
        #pragma unroll
        for (int u = 0; u < 32; ++u) hw[u] = acc[u];
    }
    __syncthreads();

    // ---- GEMM C: out = buf @ W4 + b4 -> global
    {
        const float* fl = &buf[lane * H1STR];
        #pragma unroll
        for (int u = 0; u < 32; ++u) acc[u] = b4[ob + u];
        #pragma unroll 2
        for (int k = 0; k < MID; ++k) {
            float f = fl[k];
            const float* wr = &W4[(size_t)k * MID + ob];
            #pragma unroll
            for (int u = 0; u < 32; ++u) acc[u] = fmaf(f, wr[u], acc[u]);
        }
        if (lane < nn) {
            float* orow = &out[(size_t)(n0 + lane) * OUTC + ob];
            #pragma unroll
            for (int u = 0; u < 32; ++u) orow[u] = acc[u];
        }
    }
}

extern "C" void kernel_launch(void* const* d_in, const int* in_sizes, int n_in,
                              void* d_out, int out_size, void* d_ws, size_t ws_size,
                              hipStream_t stream) {
    const float* x    = (const float*)d_in[0];
    const int*   eidx = (const int*)d_in[1];
    const float* ea   = (const float*)d_in[2];
    // d_in[3] = batch (unused)
    const float* W1 = (const float*)d_in[4];
    const float* b1 = (const float*)d_in[5];
    const float* W2 = (const float*)d_in[6];
    const float* b2 = (const float*)d_in[7];
    const float* W3 = (const float*)d_in[8];
    const float* b3 = (const float*)d_in[9];
    const float* W4 = (const float*)d_in[10];
    const float* b4 = (const float*)d_in[11];
    float* out = (float*)d_out;

    float* sumh = (float*)d_ws;                        // [NN, MID]  (sum of h1 per dst)
    float* cnt  = sumh + (size_t)NN * MID;             // [NN]

    size_t zero_bytes = ((size_t)NN * MID + NN) * sizeof(float);
    hipMemsetAsync(d_ws, 0, zero_bytes, stream);

    edge_kernel<<<NE / TILE, THREADS, 0, stream>>>(
        x, eidx, ea, W1, b1, sumh, cnt);

    node_kernel<<<(NN + TILE - 1) / TILE, THREADS, 0, stream>>>(
        sumh, cnt, W2, b2, W3, b3, W4, b4, out);
}

// Round 5
// 1276.990 us; speedup vs baseline: 8.8153x; 1.1332x over previous
//
#include <hip/hip_runtime.h>

#define NN 100000
#define NE 1600000
#define IN_CH 128
#define EAC 16
#define CAT 144      // IN_CH + EAC
#define MID 128
#define OUTC 128

#define TILE 64
#define THREADS 256
#define KHALF 72     // K-split: 72 + 72 features
#define FSTR2 73     // feat half-tile stride (odd -> 2-way max on column reads)
#define H2STR 65     // h1 half-tile stride (64 channels + 1 pad)
#define H1STR 129    // node kernel stride

__device__ __forceinline__ void atomic_add_f32(float* p, float v) {
    unsafeAtomicAdd(p, v);   // native global_atomic_add_f32 (no CAS loop)
}

// ---------------- Edge kernel: h1 = ReLU(concat(x[col], ea) @ W1 + b1); coalesced scatter-add into sumh[row] ----------------
// K-split double-pass over one 18.7 KB LDS buffer -> 8 blocks/CU.
__global__ __launch_bounds__(THREADS, 8)
void edge_kernel(const float* __restrict__ x,
                 const int* __restrict__ eidx,       // [2, NE]: [0]=row(dst), [1]=col(src)
                 const float* __restrict__ ea,       // [NE, 16]
                 const float* __restrict__ W1, const float* __restrict__ b1,
                 float* __restrict__ sumh, float* __restrict__ cnt)
{
    __shared__ float buf[TILE * FSTR2];   // 18688 B, reused: featA -> featB -> h1-half x2
    __shared__ int s_col[TILE];
    __shared__ int s_row[TILE];

    const int tid = threadIdx.x;
    const long e0 = (long)blockIdx.x * TILE;

    // ---- Phase 0: stage edge indices (NE divisible by TILE, no tail)
    if (tid < TILE)              s_col[tid] = eidx[NE + e0 + tid];
    else if (tid < 2 * TILE)     s_row[tid - TILE] = eidx[e0 + (tid - TILE)];
    __syncthreads();

    // count atomic early (drains under the gather)
    if (tid < TILE) atomic_add_f32(&cnt[s_row[tid]], 1.0f);

    const int lane = tid & 63;
    const int wv = __builtin_amdgcn_readfirstlane(tid >> 6);  // wave-uniform -> scalar W loads
    const int ob = wv * 32;                                   // wave's 32 output channels

    float acc[32];
    #pragma unroll
    for (int u = 0; u < 32; ++u) acc[u] = b1[ob + u];

    // ---- Pass A: gather x cols [0,72) ; FMA k = 0..71
    for (int i = tid; i < TILE * 18; i += THREADS) {
        int e = i / 18, seg = i - e * 18;
        float4 v = *(const float4*)&x[(size_t)s_col[e] * IN_CH + seg * 4];
        int base = e * FSTR2 + seg * 4;
        buf[base + 0] = v.x; buf[base + 1] = v.y;
        buf[base + 2] = v.z; buf[base + 3] = v.w;
    }
    __syncthreads();
    {
        const float* fl = &buf[lane * FSTR2];
        #pragma unroll 2
        for (int k = 0; k < KHALF; ++k) {
            float f = fl[k];
            const float* wr = &W1[(size_t)k * MID + ob];
            #pragma unroll
            for (int u = 0; u < 32; ++u) acc[u] = fmaf(f, wr[u], acc[u]);
        }
    }
    __syncthreads();   // everyone done reading featA

    // ---- Pass B: gather x cols [72,128) + ea[0,16) ; FMA k = 72..143
    for (int i = tid; i < TILE * 18; i += THREADS) {
        int e = i / 18, seg = i - e * 18;
        float4 v;
        if (seg < 14) v = *(const float4*)&x[(size_t)s_col[e] * IN_CH + KHALF + seg * 4];
        else          v = *(const float4*)&ea[(size_t)(e0 + e) * EAC + (seg - 14) * 4];
        int base = e * FSTR2 + seg * 4;
        buf[base + 0] = v.x; buf[base + 1] = v.y;
        buf[base + 2] = v.z; buf[base + 3] = v.w;
    }
    __syncthreads();
    {
        const float* fl = &buf[lane * FSTR2];
        #pragma unroll 2
        for (int k = 0; k < KHALF; ++k) {
            float f = fl[k];
            const float* wr = &W1[(size_t)(KHALF + k) * MID + ob];
            #pragma unroll
            for (int u = 0; u < 32; ++u) acc[u] = fmaf(f, wr[u], acc[u]);
        }
        #pragma unroll
        for (int u = 0; u < 32; ++u) acc[u] = fmaxf(acc[u], 0.f);
    }
    __syncthreads();   // everyone done reading featB

    // ---- Phase 3: transpose+scatter in two 64-channel halves (buf as h1[64][H2STR])
    #pragma unroll
    for (int half = 0; half < 2; ++half) {
        // waves owning channels [64*half, 64*half+64) stage their 32-ch slab
        if ((wv >> 1) == half) {
            float* hw = &buf[lane * H2STR + (ob - 64 * half)];
            #pragma unroll
            for (int u = 0; u < 32; ++u) hw[u] = acc[u];
        }
        __syncthreads();
        // coalesced scatter: per wave-instr, 64 lanes = 64 consecutive channels of ONE dst row
        {
            const int c = lane;           // channel within half
            #pragma unroll 4
            for (int j = 0; j < TILE / 4; ++j) {
                int e = wv + 4 * j;       // wave-uniform edge
                int dst = s_row[e];
                float v = buf[e * H2STR + c];
                atomic_add_f32(&sumh[(size_t)dst * MID + 64 * half + c], v);
            }
        }
        __syncthreads();
    }
}

// ---------------- Node kernel: mean = (sumh/max(cnt,1))@W2 + (cnt>0)*b2 ; out = ReLU(mean@W3+b3)@W4+b4 ----------------
// Single LDS buffer; GEMM results carried in registers across syncs.
__global__ __launch_bounds__(THREADS, 4)
void node_kernel(const float* __restrict__ sumh, const float* __restrict__ cnt,
                 const float* __restrict__ W2, const float* __restrict__ b2,
                 const float* __restrict__ W3, const float* __restrict__ b3,
                 const float* __restrict__ W4, const float* __restrict__ b4,
                 float* __restrict__ out)
{
    __shared__ float buf[TILE * H1STR];   // 33024 B, reused across all 3 GEMMs
    __shared__ float s_flag[TILE];

    const int tid = threadIdx.x;
    const long n0 = (long)blockIdx.x * TILE;
    const int nn = (int)min((long)TILE, (long)NN - n0);

    if (tid < TILE) {
        float c = (tid < nn) ? cnt[n0 + tid] : 0.f;
        s_flag[tid] = (c > 0.f) ? 1.f : 0.f;
    }

    // ---- load meanh = sumh / max(cnt,1) into buf
    for (int i = tid; i < TILE * 32; i += THREADS) {
        int e = i >> 5, seg = i & 31;
        float4 v = make_float4(0.f, 0.f, 0.f, 0.f);
        if (e < nn) {
            v = *(const float4*)&sumh[(size_t)(n0 + e) * MID + seg * 4];
            float inv = 1.0f / fmaxf(cnt[n0 + e], 1.0f);
            v.x *= inv; v.y *= inv; v.z *= inv; v.w *= inv;
        }
        int base = e * H1STR + seg * 4;
        buf[base + 0] = v.x; buf[base + 1] = v.y;
        buf[base + 2] = v.z; buf[base + 3] = v.w;
    }
    __syncthreads();

    const int lane = tid & 63;
    const int wv = __builtin_amdgcn_readfirstlane(tid >> 6);
    const int ob = wv * 32;

    float acc[32];

    // ---- GEMM A: mean = buf @ W2 + flag*b2 (no activation), result in regs
    {
        const float* fl = &buf[lane * H1STR];
        const float flag = s_flag[lane];
        #pragma unroll
        for (int u = 0; u < 32; ++u) acc[u] = flag * b2[ob + u];
        #pragma unroll 2
        for (int k = 0; k < MID; ++k) {
            float f = fl[k];
            const float* wr = &W2[(size_t)k * MID + ob];
            #pragma unroll
            for (int u = 0; u < 32; ++u) acc[u] = fmaf(f, wr[u], acc[u]);
        }
    }
    __syncthreads();
    {
        float* hw = &buf[lane * H1STR + ob];
        #pragma unroll
        for (int u = 0; u < 32; ++u) hw[u] = acc[u];
    }
    __syncthreads();

    // ---- GEMM B: h2 = ReLU(buf @ W3 + b3), result in regs
    {
        const float* fl = &buf[lane * H1STR];
        #pragma unroll
        for (int u = 0; u < 32; ++u) acc[u] = b3[ob + u];
        #pragma unroll 2
        for (int k = 0; k < MID; ++k) {
            float f = fl[k];
            const float* wr = &W3[(size_t)k * MID + ob];
            #pragma unroll
            for (int u = 0; u < 32; ++u) acc[u] = fmaf(f, wr[u], acc[u]);
        }
        #pragma unroll
        for (int u = 0; u < 32; ++u) acc[u] = fmaxf(acc[u], 0.f);
    }
    __syncthreads();
    {
        float* hw = &buf[lane * H1STR + ob];
        #pragma unroll
        for (int u = 0; u < 32; ++u) hw[u] = acc[u];
    }
    __syncthreads();

    // ---- GEMM C: out = buf @ W4 + b4 -> global
    {
        const float* fl = &buf[lane * H1STR];
        #pragma unroll
        for (int u = 0; u < 32; ++u) acc[u] = b4[ob + u];
        #pragma unroll 2
        for (int k = 0; k < MID; ++k) {
            float f = fl[k];
            const float* wr = &W4[(size_t)k * MID + ob];
            #pragma unroll
            for (int u = 0; u < 32; ++u) acc[u] = fmaf(f, wr[u], acc[u]);
        }
        if (lane < nn) {
            float* orow = &out[(size_t)(n0 + lane) * OUTC + ob];
            #pragma unroll
            for (int u = 0; u < 32; ++u) orow[u] = acc[u];
        }
    }
}

extern "C" void kernel_launch(void* const* d_in, const int* in_sizes, int n_in,
                              void* d_out, int out_size, void* d_ws, size_t ws_size,
                              hipStream_t stream) {
    const float* x    = (const float*)d_in[0];
    const int*   eidx = (const int*)d_in[1];
    const float* ea   = (const float*)d_in[2];
    // d_in[3] = batch (unused)
    const float* W1 = (const float*)d_in[4];
    const float* b1 = (const float*)d_in[5];
    const float* W2 = (const float*)d_in[6];
    const float* b2 = (const float*)d_in[7];
    const float* W3 = (const float*)d_in[8];
    const float* b3 = (const float*)d_in[9];
    const float* W4 = (const float*)d_in[10];
    const float* b4 = (const float*)d_in[11];
    float* out = (float*)d_out;

    float* sumh = (float*)d_ws;                        // [NN, MID]  (sum of h1 per dst)
    float* cnt  = sumh + (size_t)NN * MID;             // [NN]

    size_t zero_bytes = ((size_t)NN * MID + NN) * sizeof(float);
    hipMemsetAsync(d_ws, 0, zero_bytes, stream);

    edge_kernel<<<NE / TILE, THREADS, 0, stream>>>(
        x, eidx, ea, W1, b1, sumh, cnt);

    node_kernel<<<(NN + TILE - 1) / TILE, THREADS, 0, stream>>>(
        sumh, cnt, W2, b2, W3, b3, W4, b4, out);
}

// Round 7
// 1095.482 us; speedup vs baseline: 10.2759x; 1.1657x over previous
//
#include <hip/hip_runtime.h>

#define NN 100000
#define NE 1600000
#define IN_CH 128
#define EAC 16
#define CAT 144      // IN_CH + EAC
#define MID 128
#define OUTC 128

#define TILE 64
#define THREADS 256
#define H2STR 65     // h1 scatter-staging stride
#define H1STR 129    // node kernel stride

typedef _Float16 f16x8  __attribute__((ext_vector_type(8)));
typedef _Float16 f16x16 __attribute__((ext_vector_type(16)));
typedef float    f32x4  __attribute__((ext_vector_type(4)));

#define NKT 5        // K-tiles of 32 (144 -> 4 full + 1 half)
// feat2 fragment-major u32 layout: rb(4) x [kt0..3: 512 u32, kt4: 256 u32] = 2304 u32/rb
#define RBSZ 2304
#define FEAT2_U32 (4 * RBSZ)   // 9216 u32 = 36864 B

__device__ __forceinline__ void atomic_add_f32(float* p, float v) {
    unsafeAtomicAdd(p, v);   // native global_atomic_add_f32
}

// split x into f16 hi + f16 lo*2^8, packed (hi | lo<<16)
__device__ __forceinline__ unsigned int split_pack(float x) {
    _Float16 hi = (_Float16)x;
    _Float16 lo = (_Float16)((x - (float)hi) * 256.0f);
    union { _Float16 h[2]; unsigned int u; } q;
    q.h[0] = hi; q.h[1] = lo;
    return q.u;
}

// ---------------- Prep: split W1 into f16 hi / lo*2^8 in MFMA B-fragment order ----------------
// Bp layout: [(cb*5 + kt)*64 + lane]*8 + j ; value = W1[k][c], k = kt*32+(lane>>4)*8+j, c = cb*16+(lane&15)
__global__ void prep_kernel(const float* __restrict__ W1,
                            _Float16* __restrict__ Bhi, _Float16* __restrict__ Blo)
{
    int idx = blockIdx.x * 256 + threadIdx.x;   // 0..20479
    if (idx >= 8 * NKT * 64 * 8) return;
    int j = idx & 7;
    int l = (idx >> 3) & 63;
    int t = idx >> 9;          // cb*5 + kt
    int kt = t % NKT;
    int cb = t / NKT;
    int k = kt * 32 + ((l >> 4) << 3) + j;
    int c = (cb << 4) + (l & 15);
    float w = (k < CAT) ? W1[(size_t)k * MID + c] : 0.f;
    _Float16 hi = (_Float16)w;
    _Float16 lo = (_Float16)((w - (float)hi) * 256.0f);
    Bhi[idx] = hi;
    Blo[idx] = lo;
}

// ---------------- Edge kernel: h1 = ReLU(concat(x[col],ea) @ W1 + b1) via split-f16 MFMA; coalesced atomic scatter ----------------
__global__ __launch_bounds__(THREADS, 4)
void edge_kernel(const float* __restrict__ x,
                 const int* __restrict__ eidx,       // [2, NE]: [0]=row(dst), [1]=col(src)
                 const float* __restrict__ ea,       // [NE, 16]
                 const _Float16* __restrict__ Bhi, const _Float16* __restrict__ Blo,
                 const float* __restrict__ b1,
                 float* __restrict__ sumh, float* __restrict__ cnt)
{
    __shared__ __align__(16) unsigned int feat2[FEAT2_U32];   // 36864 B, reused for scatter staging
    __shared__ int s_col[TILE];
    __shared__ int s_row[TILE];

    const int tid = threadIdx.x;
    const long e0 = (long)blockIdx.x * TILE;

    if (tid < TILE)              s_col[tid] = eidx[NE + e0 + tid];
    else if (tid < 2 * TILE)     s_row[tid - TILE] = eidx[e0 + (tid - TILE)];
    __syncthreads();

    if (tid < TILE) atomic_add_f32(&cnt[s_row[tid]], 1.0f);   // drains under gather

    // ---- gather + split-convert into fragment-major LDS (64 edges x 36 float4)
    for (int i = tid; i < TILE * 36; i += THREADS) {
        int e = i / 36, s = i - e * 36;
        float4 v;
        if (s < 32) v = *(const float4*)&x[(size_t)s_col[e] * IN_CH + s * 4];
        else        v = *(const float4*)&ea[(size_t)(e0 + e) * EAC + (s - 32) * 4];
        int k = s * 4;                       // 0..143, k%4==0
        int rb = e >> 4, m = e & 15, kt = k >> 5;
        int base = rb * RBSZ + kt * 512 + (m + (((k & 31) >> 3) << 4)) * 8 + (k & 7);
        uint4 p;
        p.x = split_pack(v.x); p.y = split_pack(v.y);
        p.z = split_pack(v.z); p.w = split_pack(v.w);
        *(uint4*)&feat2[base] = p;           // 16B aligned (base%4==0)
    }
    __syncthreads();

    const int l  = tid & 63;
    const int wv = tid >> 6;

    // ---- MFMA: each wave computes 64 edges x 32 channels (cb = 2*wv, 2*wv+1)
    f32x4 acc1[2][4] = {};   // hi*HI
    f32x4 acc2[2][4] = {};   // (hi*LO' + lo'*HI), scaled 2^8
    const _Float16* fp = (const _Float16*)feat2;

    #pragma unroll
    for (int kt = 0; kt < NKT; ++kt) {
        f16x8 bh[2], bl[2];
        #pragma unroll
        for (int cb = 0; cb < 2; ++cb) {
            int fi = (((2 * wv + cb) * NKT + kt) * 64 + l) * 8;
            bh[cb] = *(const f16x8*)(Bhi + fi);
            bl[cb] = *(const f16x8*)(Blo + fi);
        }
        #pragma unroll
        for (int rb = 0; rb < 4; ++rb) {
            f16x8 ahi, alo;
            if (kt < 4 || l < 32) {
                int abase = rb * RBSZ + kt * 512 + l * 8;      // u32 index
                f16x16 av = *(const f16x16*)(fp + abase * 2);  // 32B = 2x ds_read_b128
                ahi = __builtin_shufflevector(av, av, 0, 2, 4, 6, 8, 10, 12, 14);
                alo = __builtin_shufflevector(av, av, 1, 3, 5, 7, 9, 11, 13, 15);
            } else {
                ahi = (f16x8)0; alo = (f16x8)0;                // k >= 144 pad
            }
            #pragma unroll
            for (int cb = 0; cb < 2; ++cb) {
                acc1[cb][rb] = __builtin_amdgcn_mfma_f32_16x16x32_f16(ahi, bh[cb], acc1[cb][rb], 0, 0, 0);
                acc2[cb][rb] = __builtin_amdgcn_mfma_f32_16x16x32_f16(ahi, bl[cb], acc2[cb][rb], 0, 0, 0);
                acc2[cb][rb] = __builtin_amdgcn_mfma_f32_16x16x32_f16(alo, bh[cb], acc2[cb][rb], 0, 0, 0);
            }
        }
    }
    __syncthreads();   // all waves done reading feat2

    // ---- epilogue + two-half coalesced scatter (reuse feat2 as h1[64][H2STR] f32)
    float* h1 = (float*)feat2;
    #pragma unroll
    for (int half = 0; half < 2; ++half) {
        if ((wv >> 1) == half) {
            #pragma unroll
            for (int cb = 0; cb < 2; ++cb) {
                int ch = 32 * wv + 16 * cb + (l & 15);         // global channel
                float bias = b1[ch];
                int cl = ch - 64 * half;                       // channel within half
                #pragma unroll
                for (int rb = 0; rb < 4; ++rb) {
                    #pragma unroll
                    for (int r = 0; r < 4; ++r) {
                        int m = 16 * rb + ((l >> 4) << 2) + r; // edge index
                        float hv = acc1[cb][rb][r] + acc2[cb][rb][r] * (1.0f / 256.0f) + bias;
                        h1[m * H2STR + cl] = fmaxf(hv, 0.f);
                    }
                }
            }
        }
        __syncthreads();
        // coalesced scatter: per wave-instr, 64 lanes = 64 consecutive channels of ONE dst row
        #pragma unroll 4
        for (int jj = 0; jj < TILE / 4; ++jj) {
            int e = wv + 4 * jj;
            int dst = s_row[e];
            float v = h1[e * H2STR + l];
            atomic_add_f32(&sumh[(size_t)dst * MID + 64 * half + l], v);
        }
        __syncthreads();
    }
}

// ---------------- Node kernel: mean = (sumh/max(cnt,1))@W2 + (cnt>0)*b2 ; out = ReLU(mean@W3+b3)@W4+b4 ----------------
__global__ __launch_bounds__(THREADS, 4)
void node_kernel(const float* __restrict__ sumh, const float* __restrict__ cnt,
                 const float* __restrict__ W2, const float* __restrict__ b2,
                 const float* __restrict__ W3, const float* __restrict__ b3,
                 const float* __restrict__ W4, const float* __restrict__ b4,
                 float* __restrict__ out)
{
    __shared__ float buf[TILE * H1STR];   // 33024 B, reused across all 3 GEMMs
    __shared__ float s_flag[TILE];

    const int tid = threadIdx.x;
    const long n0 = (long)blockIdx.x * TILE;
    const int nn = (int)min((long)TILE, (long)NN - n0);

    if (tid < TILE) {
        float c = (tid < nn) ? cnt[n0 + tid] : 0.f;
        s_flag[tid] = (c > 0.f) ? 1.f : 0.f;
    }

    for (int i = tid; i < TILE * 32; i += THREADS) {
        int e = i >> 5, seg = i & 31;
        float4 v = make_float4(0.f, 0.f, 0.f, 0.f);
        if (e < nn) {
            v = *(const float4*)&sumh[(size_t)(n0 + e) * MID + seg * 4];
            float inv = 1.0f / fmaxf(cnt[n0 + e], 1.0f);
            v.x *= inv; v.y *= inv; v.z *= inv; v.w *= inv;
        }
        int base = e * H1STR + seg * 4;
        buf[base + 0] = v.x; buf[base + 1] = v.y;
        buf[base + 2] = v.z; buf[base + 3] = v.w;
    }
    __syncthreads();

    const int lane = tid & 63;
    const int wv = __builtin_amdgcn_readfirstlane(tid >> 6);
    const int ob = wv * 32;

    float acc[32];

    // ---- GEMM A: mean = buf @ W2 + flag*b2
    {
        const float* fl = &buf[lane * H1STR];
        const float flag = s_flag[lane];
        #pragma unroll
        for (int u = 0; u < 32; ++u) acc[u] = flag * b2[ob + u];
        #pragma unroll 2
        for (int k = 0; k < MID; ++k) {
            float f = fl[k];
            const float* wr = &W2[(size_t)k * MID + ob];
            #pragma unroll
            for (int u = 0; u < 32; ++u) acc[u] = fmaf(f, wr[u], acc[u]);
        }
    }
    __syncthreads();
    {
        float* hw = &buf[lane * H1STR + ob];
        #pragma unroll
        for (int u = 0; u < 32; ++u) hw[u] = acc[u];
    }
    __syncthreads();

    // ---- GEMM B: h2 = ReLU(buf @ W3 + b3)
    {
        const float* fl = &buf[lane * H1STR];
        #pragma unroll
        for (int u = 0; u < 32; ++u) acc[u] = b3[ob + u];
        #pragma unroll 2
        for (int k = 0; k < MID; ++k) {
            float f = fl[k];
            const float* wr = &W3[(size_t)k * MID + ob];
            #pragma unroll
            for (int u = 0; u < 32; ++u) acc[u] = fmaf(f, wr[u], acc[u]);
        }
        #pragma unroll
        for (int u = 0; u < 32; ++u) acc[u] = fmaxf(acc[u], 0.f);
    }
    __syncthreads();
    {
        float* hw = &buf[lane * H1STR + ob];
        #pragma unroll
        for (int u = 0; u < 32; ++u) hw[u] = acc[u];
    }
    __syncthreads();

    // ---- GEMM C: out = buf @ W4 + b4
    {
        const float* fl = &buf[lane * H1STR];
        #pragma unroll
        for (int u = 0; u < 32; ++u) acc[u] = b4[ob + u];
        #pragma unroll 2
        for (int k = 0; k < MID; ++k) {
            float f = fl[k];
            const float* wr = &W4[(size_t)k * MID + ob];
            #pragma unroll
            for (int u = 0; u < 32; ++u) acc[u] = fmaf(f, wr[u], acc[u]);
        }
        if (lane < nn) {
            float* orow = &out[(size_t)(n0 + lane) * OUTC + ob];
            #pragma unroll
            for (int u = 0; u < 32; ++u) orow[u] = acc[u];
        }
    }
}

extern "C" void kernel_launch(void* const* d_in, const int* in_sizes, int n_in,
                              void* d_out, int out_size, void* d_ws, size_t ws_size,
                              hipStream_t stream) {
    const float* x    = (const float*)d_in[0];
    const int*   eidx = (const int*)d_in[1];
    const float* ea   = (const float*)d_in[2];
    // d_in[3] = batch (unused)
    const float* W1 = (const float*)d_in[4];
    const float* b1 = (const float*)d_in[5];
    const float* W2 = (const float*)d_in[6];
    const float* b2 = (const float*)d_in[7];
    const float* W3 = (const float*)d_in[8];
    const float* b3 = (const float*)d_in[9];
    const float* W4 = (const float*)d_in[10];
    const float* b4 = (const float*)d_in[11];
    float* out = (float*)d_out;

    float* sumh = (float*)d_ws;                        // [NN, MID]
    float* cnt  = sumh + (size_t)NN * MID;             // [NN]
    _Float16* Bhi = (_Float16*)(cnt + NN);             // [8*5*64*8] = 20480 f16
    _Float16* Blo = Bhi + 8 * NKT * 64 * 8;

    size_t zero_bytes = ((size_t)NN * MID + NN) * sizeof(float);
    hipMemsetAsync(d_ws, 0, zero_bytes, stream);

    prep_kernel<<<80, 256, 0, stream>>>(W1, Bhi, Blo);

    edge_kernel<<<NE / TILE, THREADS, 0, stream>>>(
        x, eidx, ea, Bhi, Blo, b1, sumh, cnt);

    node_kernel<<<(NN + TILE - 1) / TILE, THREADS, 0, stream>>>(
        sumh, cnt, W2, b2, W3, b3, W4, b4, out);
}